// Round 3
// baseline (496.140 us; speedup 1.0000x reference)
//
#include <hip/hip_runtime.h>
#include <math.h>

#define HW 4096
#define NB 32
#define VD 16

// ws layout (float offsets) — counters zeroed by k_init every launch
#define OFF_M0P   0        // 32 b * 16 blocks * 16 ch per-block partial sums
#define OFF_MSP   8192     // 32 b * 16 blocks mantissa partials
#define OFF_WT    8704     // 512*16 transposed root_w (wt[c][o], c-major)
#define OFF_CNT   16896    // 33 ints: [0..31] per-batch arrival, [32] mantissa

#define LD_AGENT(p)     __hip_atomic_load((p), __ATOMIC_RELAXED, __HIP_MEMORY_SCOPE_AGENT)
#define ST_AGENT(p, v)  __hip_atomic_store((p), (v), __ATOMIC_RELAXED, __HIP_MEMORY_SCOPE_AGENT)

// Transpose root_w + zero the counters. Runs before k_fused (stream order).
__global__ __launch_bounds__(256) void k_init(const float* __restrict__ rw,
                                              float* __restrict__ ws) {
    int i = blockIdx.x * 256 + threadIdx.x;   // 8192 elements
    if (i < 512 * VD) {
        int c = i >> 4, o = i & 15;
        ws[OFF_WT + i] = rw[o * 512 + c];
    }
    if (blockIdx.x == 0 && threadIdx.x < 33)
        ((int*)(ws + OFF_CNT))[threadIdx.x] = 0;
}

// Fused: root conv (f0 stays in registers) -> per-batch device barrier on the
// 16x16 mean partials -> redundant per-block tree walk -> epilogue on registers
// -> global mantissa finish. 512 blocks, all co-resident (launch_bounds 256,2:
// >=2 blocks/CU * 256 CUs = 512 >= grid), so the spin cannot deadlock.
// ALL cross-block payload (m0p, msp) uses agent-scope atomic load/store —
// plain stores + volatile loads were served stale across XCD L2s (round-2 fail).
__global__ __launch_bounds__(256, 2) void k_fused(const float* __restrict__ feat,
                                                  const float* __restrict__ rb,
                                                  const float* __restrict__ lw,
                                                  const float* __restrict__ lb,
                                                  const float* __restrict__ m1w,
                                                  const float* __restrict__ m1b,
                                                  const float* __restrict__ m2w,
                                                  const float* __restrict__ m2b,
                                                  float* __restrict__ ws,
                                                  float* __restrict__ out) {
    const int b  = blockIdx.y;
    const int bx = blockIdx.x;                 // 16 px blocks per batch
    const int t  = threadIdx.x;
    const int px = bx * 256 + t;

    __shared__ float s1w[1024], s1b[64], s2w[64];
    __shared__ float red[4][VD];
    __shared__ float lm[15][VD];
    __shared__ float Wst[256];
    __shared__ float sM[256], scb[VD];
    __shared__ float rs[4];
    __shared__ int   path[5];
    __shared__ int   lastflag;

    // stage epilogue weights early (tiny, L2-hot)
    for (int i = t; i < 1024; i += 256) s1w[i] = m1w[i];
    if (t < 64) { s1b[t] = m1b[t]; s2w[t] = m2w[t]; }

    // ---------------- phase A: root conv, f0 in registers ----------------
    const float* fp = feat + (size_t)b * 512 * HW + px;
    const float* wt = ws + OFF_WT;

    float acc[VD];
#pragma unroll
    for (int o = 0; o < VD; ++o) acc[o] = rb[o];

    float cur[8], nxt[8];
#pragma unroll
    for (int k = 0; k < 8; ++k) cur[k] = fp[(size_t)k * HW];

    for (int c = 0; c < 512; c += 8) {
        if (c + 8 < 512) {
#pragma unroll
            for (int k = 0; k < 8; ++k)
                nxt[k] = fp[(size_t)(c + 8 + k) * HW];
        }
#pragma unroll
        for (int g = 0; g < 2; ++g) {
            const float* wr = wt + (size_t)(c + g * 4) * VD;  // 64 uniform floats
#pragma unroll
            for (int k = 0; k < 4; ++k) {
                float x = cur[g * 4 + k];
#pragma unroll
                for (int o = 0; o < VD; ++o)
                    acc[o] = fmaf(wr[k * VD + o], x, acc[o]);
            }
        }
#pragma unroll
        for (int k = 0; k < 8; ++k) cur[k] = nxt[k];
    }

    // per-block mean partials -> global exchange buffer (coherent stores)
    const int lane = t & 63, wv = t >> 6;
#pragma unroll
    for (int o = 0; o < VD; ++o) {
        float v = acc[o];
#pragma unroll
        for (int off = 32; off > 0; off >>= 1) v += __shfl_down(v, off);
        if (lane == 0) red[wv][o] = v;
    }
    __syncthreads();
    float* m0p = ws + OFF_M0P;
    if (t < VD)
        ST_AGENT(&m0p[(b * 16 + bx) * VD + t],
                 red[0][t] + red[1][t] + red[2][t] + red[3][t]);

    // ---------------- phase B: per-batch arrival barrier ----------------
    int* cnt = (int*)(ws + OFF_CNT);
    __threadfence();                                   // belt-and-braces release
    if (t == 0) {
        __hip_atomic_fetch_add(cnt + b, 1, __ATOMIC_RELEASE,
                               __HIP_MEMORY_SCOPE_AGENT);
        while (__hip_atomic_load(cnt + b, __ATOMIC_ACQUIRE,
                                 __HIP_MEMORY_SCOPE_AGENT) < 16)
            __builtin_amdgcn_s_sleep(2);
    }
    __syncthreads();
    __threadfence();                                   // belt-and-braces acquire

    // ---------------- phase C: tree walk (redundant per block) ----------
    const int Soff[5] = {0, 1, 3, 6, 10};
    const int LOFF[4] = {0, 2, 5, 9};

    if (t < VD) {
        float s = 0.f;
        for (int k = 0; k < 16; ++k)
            s += LD_AGENT(&m0p[((size_t)b * 16 + k) * VD + t]);   // coherent reads
        lm[0][t] = s * (1.0f / HW);
    }
    __syncthreads();

    for (int l = 1; l <= 4; ++l) {
        if (t < VD) {
            for (int n = 0; n <= l; ++n) {
                int pl = (n - 1 < 0) ? 0 : (n - 1);
                int pr = (n < l - 1) ? n : (l - 1);
                const float* A = lm[Soff[l - 1] + pl];
                const float* R = lm[Soff[l - 1] + pr];
                bool takeR = false;
                if (pl != pr) {
                    float ln = 0.f, rn = 0.f;
                    for (int k = 0; k < VD; ++k) { ln += A[k] * A[k]; rn += R[k] * R[k]; }
                    takeR = sqrtf(rn) > sqrtf(ln);
                }
                int widx = LOFF[l - 1] + n;
                float s = lb[widx * VD + t];
                for (int k = 0; k < VD; ++k) {
                    float pk = takeR ? R[k] : A[k];
                    s += lw[(widx * VD + t) * VD + k] * pk;
                }
                lm[Soff[l] + n][t] = s;
            }
        }
        __syncthreads();
    }

    if (t == 0) {
        float best = -1.f; int bi = 0;
        for (int n = 0; n < 5; ++n) {
            float s = 0.f;
            for (int k = 0; k < VD; ++k) { float v = lm[10 + n][k]; s += v * v; }
            float lg = sqrtf(s);
            if (bx == 0) out[b * 5 + n] = lg;          // class_logits
            if (lg > best) { best = lg; bi = n; }
        }
        if (bx == 0) out[192 + b] = (float)bi;         // selected_class
        int node = bi;
        for (int l = 4; l >= 1; --l) {
            path[l] = LOFF[l - 1] + node;
            int pl = (node - 1 < 0) ? 0 : (node - 1);
            int pr = (node < l - 1) ? node : (l - 1);
            if (pl == pr) node = pl;
            else {
                float ln = 0.f, rn = 0.f;
                for (int k = 0; k < VD; ++k) {
                    float a = lm[Soff[l - 1] + pl][k], r = lm[Soff[l - 1] + pr][k];
                    ln += a * a; rn += r * r;
                }
                node = (sqrtf(rn) > sqrtf(ln)) ? pr : pl;
            }
        }
    }
    __syncthreads();

    Wst[t] = lw[path[1] * 256 + t];
    __syncthreads();
    float Mc[VD], cc[VD];
    if (t < VD) {
        for (int i = 0; i < VD; ++i) Mc[i] = Wst[i * VD + t];
        for (int i = 0; i < VD; ++i) cc[i] = lb[path[1] * VD + i];
    }
    for (int l = 2; l <= 4; ++l) {
        __syncthreads();
        Wst[t] = lw[path[l] * 256 + t];
        __syncthreads();
        if (t < VD) {
            float nM[VD], nc[VD];
            for (int i = 0; i < VD; ++i) {
                float sm = 0.f, sc2 = 0.f;
                for (int k = 0; k < VD; ++k) {
                    float w = Wst[i * VD + k];
                    sm += w * Mc[k]; sc2 += w * cc[k];
                }
                nM[i] = sm; nc[i] = sc2 + lb[path[l] * VD + i];
            }
            for (int i = 0; i < VD; ++i) { Mc[i] = nM[i]; cc[i] = nc[i]; }
        }
    }
    if (t < VD) {
        for (int i = 0; i < VD; ++i) sM[i * VD + t] = Mc[i];
        if (t == 0) for (int i = 0; i < VD; ++i) scb[i] = cc[i];
    }
    __syncthreads();

    // ---------------- phase D: epilogue on registers ---------------------
    float v[VD];
#pragma unroll
    for (int i = 0; i < VD; ++i) {
        float s = scb[i];
#pragma unroll
        for (int j = 0; j < VD; ++j) s += sM[i * VD + j] * acc[j];
        v[i] = s;
    }
    float n2 = 0.f;
#pragma unroll
    for (int i = 0; i < VD; ++i) n2 += v[i] * v[i];
    float inv = 1.f / (sqrtf(n2) + 1e-8f);
#pragma unroll
    for (int i = 0; i < VD; ++i) v[i] *= inv;

    float psum = m2b[0];
#pragma unroll 8
    for (int o = 0; o < 64; ++o) {
        float h = s1b[o];
#pragma unroll
        for (int i = 0; i < VD; ++i) h += s1w[o * VD + i] * v[i];
        h = fmaxf(h, 0.f);
        psum += s2w[o] * h;
    }

#pragma unroll
    for (int off = 32; off > 0; off >>= 1) psum += __shfl_down(psum, off);
    if (lane == 0) rs[wv] = psum;
    __syncthreads();

    float* msp = ws + OFF_MSP;
    if (t == 0) {
        ST_AGENT(&msp[b * 16 + bx], rs[0] + rs[1] + rs[2] + rs[3]);  // coherent
        __threadfence();
        int old = __hip_atomic_fetch_add(cnt + 32, 1, __ATOMIC_ACQ_REL,
                                         __HIP_MEMORY_SCOPE_AGENT);
        lastflag = (old == NB * 16 - 1);
    }
    __syncthreads();

    if (lastflag) {
        __threadfence();
        if (t < NB) {
            float m = 0.f;
            for (int k = 0; k < 16; ++k)
                m += LD_AGENT(&msp[t * 16 + k]);                     // coherent
            m *= (1.0f / HW);
            out[160 + t] = (1.0f / (1.0f + expf(-m))) * 0.75f + 0.75f;
        }
    }
}

extern "C" void kernel_launch(void* const* d_in, const int* in_sizes, int n_in,
                              void* d_out, int out_size, void* d_ws, size_t ws_size,
                              hipStream_t stream) {
    const float* feat    = (const float*)d_in[0];
    const float* root_w  = (const float*)d_in[1];
    const float* root_b  = (const float*)d_in[2];
    const float* level_w = (const float*)d_in[3];
    const float* level_b = (const float*)d_in[4];
    const float* m1w     = (const float*)d_in[5];
    const float* m1b     = (const float*)d_in[6];
    const float* m2w     = (const float*)d_in[7];
    const float* m2b     = (const float*)d_in[8];
    float* ws  = (float*)d_ws;
    float* out = (float*)d_out;

    k_init<<<32, 256, 0, stream>>>(root_w, ws);
    k_fused<<<dim3(16, NB), 256, 0, stream>>>(feat, root_b, level_w, level_b,
                                              m1w, m1b, m2w, m2b, ws, out);
}

// Round 4
// 399.431 us; speedup vs baseline: 1.2421x; 1.2421x over previous
//
#include <hip/hip_runtime.h>
#include <math.h>

#define HW 4096
#define NB 32
#define VD 16

// ws layout (float offsets)
#define OFF_M0P   0        // 32 b * 16 blocks * 16 ch per-block partial sums
#define OFF_MSP   8192     // 32 b * 8 blocks mantissa partials
#define OFF_WT    8448     // 512*16 transposed root_w (wt[c][o], c-major)
#define OFF_CNT   16640    // 1 int: mantissa arrival counter (zeroed by k_init)
#define OFF_P     16704    // f0: 32*16*4096 floats (8 MiB)

#define LD_AGENT(p)     __hip_atomic_load((p), __ATOMIC_RELAXED, __HIP_MEMORY_SCOPE_AGENT)
#define ST_AGENT(p, v)  __hip_atomic_store((p), (v), __ATOMIC_RELAXED, __HIP_MEMORY_SCOPE_AGENT)

// Transpose root_w + zero the mantissa counter. Runs first in stream order.
__global__ __launch_bounds__(256) void k_init(const float* __restrict__ rw,
                                              float* __restrict__ ws) {
    int i = blockIdx.x * 256 + threadIdx.x;   // 8192 elements
    if (i < 512 * VD) {
        int c = i >> 4, o = i & 15;
        ws[OFF_WT + i] = rw[o * 512 + c];
    }
    if (blockIdx.x == 0 && threadIdx.x == 0)
        *(int*)(ws + OFF_CNT) = 0;
}

// Root conv (proven round-1 version): 1 px/thread, all 512 channels, f0 write.
// 512 blocks (16 px-blocks x 32 b) = 2 blocks/CU, 8 waves/CU.
__global__ __launch_bounds__(256) void k_root(const float* __restrict__ feat,
                                              const float* __restrict__ wt,
                                              const float* __restrict__ rb,
                                              float* __restrict__ f0,
                                              float* __restrict__ m0p) {
    const int b  = blockIdx.y;
    const int bx = blockIdx.x;                 // 16 px blocks
    const int t  = threadIdx.x;
    const int px = bx * 256 + t;
    const float* fp = feat + (size_t)b * 512 * HW + px;

    float acc[VD];
#pragma unroll
    for (int o = 0; o < VD; ++o) acc[o] = rb[o];

    float cur[8], nxt[8];
#pragma unroll
    for (int k = 0; k < 8; ++k) cur[k] = fp[(size_t)k * HW];

    for (int c = 0; c < 512; c += 8) {
        if (c + 8 < 512) {
#pragma unroll
            for (int k = 0; k < 8; ++k)
                nxt[k] = fp[(size_t)(c + 8 + k) * HW];
        }
#pragma unroll
        for (int g = 0; g < 2; ++g) {
            const float* wr = wt + (size_t)(c + g * 4) * VD;  // 64 uniform floats
#pragma unroll
            for (int k = 0; k < 4; ++k) {
                float x = cur[g * 4 + k];
#pragma unroll
                for (int o = 0; o < VD; ++o)
                    acc[o] = fmaf(wr[k * VD + o], x, acc[o]);
            }
        }
#pragma unroll
        for (int k = 0; k < 8; ++k) cur[k] = nxt[k];
    }

    float* op = f0 + (size_t)b * VD * HW + px;
#pragma unroll
    for (int o = 0; o < VD; ++o) op[(size_t)o * HW] = acc[o];

    // per-block mean partials (16 blocks per batch)
    __shared__ float red[4][VD];
    const int lane = t & 63, wv = t >> 6;
#pragma unroll
    for (int o = 0; o < VD; ++o) {
        float v = acc[o];
#pragma unroll
        for (int off = 32; off > 0; off >>= 1) v += __shfl_down(v, off);
        if (lane == 0) red[wv][o] = v;
    }
    __syncthreads();
    if (t < VD)
        m0p[(b * 16 + bx) * VD + t] =
            red[0][t] + red[1][t] + red[2][t] + red[3][t];
}

// Tree (redundant per block, reads completed m0p across kernel boundary)
// + epilogue + last-block mantissa finish. 8 px-blocks x 32 batches.
__global__ __launch_bounds__(256) void k_final(const float* __restrict__ f0,
                                               const float* __restrict__ lw,
                                               const float* __restrict__ lb,
                                               const float* __restrict__ m1w,
                                               const float* __restrict__ m1b,
                                               const float* __restrict__ m2w,
                                               const float* __restrict__ m2b,
                                               float* __restrict__ ws,
                                               float* __restrict__ out) {
    const int b  = blockIdx.y;
    const int bx = blockIdx.x;                 // 8 px blocks per batch
    const int t  = threadIdx.x;

    __shared__ float s1w[1024], s1b[64], s2w[64];
    __shared__ float lm[15][VD];
    __shared__ float Wst[256];
    __shared__ float sM[256], scb[VD];
    __shared__ float rs[4];
    __shared__ int   path[5];
    __shared__ int   lastflag;

    // issue f0 loads early — latency hides under the tree walk
    const size_t base = (size_t)b * VD * HW + bx * 512 + t * 2;
    float2 f[VD];
#pragma unroll
    for (int j = 0; j < VD; ++j)
        f[j] = *(const float2*)(f0 + base + (size_t)j * HW);

    for (int i = t; i < 1024; i += 256) s1w[i] = m1w[i];
    if (t < 64) { s1b[t] = m1b[t]; s2w[t] = m2w[t]; }

    // ---------------- tree walk (redundant per block) --------------------
    const int Soff[5] = {0, 1, 3, 6, 10};
    const int LOFF[4] = {0, 2, 5, 9};

    if (t < VD) {
        const float* mp = ws + OFF_M0P + (size_t)b * 16 * VD + t;
        float s = 0.f;
        for (int k = 0; k < 16; ++k) s += mp[k * VD];
        lm[0][t] = s * (1.0f / HW);
    }
    __syncthreads();

    for (int l = 1; l <= 4; ++l) {
        if (t < VD) {
            for (int n = 0; n <= l; ++n) {
                int pl = (n - 1 < 0) ? 0 : (n - 1);
                int pr = (n < l - 1) ? n : (l - 1);
                const float* A = lm[Soff[l - 1] + pl];
                const float* R = lm[Soff[l - 1] + pr];
                bool takeR = false;
                if (pl != pr) {
                    float ln = 0.f, rn = 0.f;
                    for (int k = 0; k < VD; ++k) { ln += A[k] * A[k]; rn += R[k] * R[k]; }
                    takeR = sqrtf(rn) > sqrtf(ln);
                }
                int widx = LOFF[l - 1] + n;
                float s = lb[widx * VD + t];
                for (int k = 0; k < VD; ++k) {
                    float pk = takeR ? R[k] : A[k];
                    s += lw[(widx * VD + t) * VD + k] * pk;
                }
                lm[Soff[l] + n][t] = s;
            }
        }
        __syncthreads();
    }

    if (t == 0) {
        float best = -1.f; int bi = 0;
        for (int n = 0; n < 5; ++n) {
            float s = 0.f;
            for (int k = 0; k < VD; ++k) { float v = lm[10 + n][k]; s += v * v; }
            float lg = sqrtf(s);
            if (bx == 0) out[b * 5 + n] = lg;          // class_logits
            if (lg > best) { best = lg; bi = n; }
        }
        if (bx == 0) out[192 + b] = (float)bi;         // selected_class
        int node = bi;
        for (int l = 4; l >= 1; --l) {
            path[l] = LOFF[l - 1] + node;
            int pl = (node - 1 < 0) ? 0 : (node - 1);
            int pr = (node < l - 1) ? node : (l - 1);
            if (pl == pr) node = pl;
            else {
                float ln = 0.f, rn = 0.f;
                for (int k = 0; k < VD; ++k) {
                    float a = lm[Soff[l - 1] + pl][k], r = lm[Soff[l - 1] + pr][k];
                    ln += a * a; rn += r * r;
                }
                node = (sqrtf(rn) > sqrtf(ln)) ? pr : pl;
            }
        }
    }
    __syncthreads();

    Wst[t] = lw[path[1] * 256 + t];
    __syncthreads();
    float Mc[VD], cc[VD];
    if (t < VD) {
        for (int i = 0; i < VD; ++i) Mc[i] = Wst[i * VD + t];
        for (int i = 0; i < VD; ++i) cc[i] = lb[path[1] * VD + i];
    }
    for (int l = 2; l <= 4; ++l) {
        __syncthreads();
        Wst[t] = lw[path[l] * 256 + t];
        __syncthreads();
        if (t < VD) {
            float nM[VD], nc[VD];
            for (int i = 0; i < VD; ++i) {
                float sm = 0.f, sc2 = 0.f;
                for (int k = 0; k < VD; ++k) {
                    float w = Wst[i * VD + k];
                    sm += w * Mc[k]; sc2 += w * cc[k];
                }
                nM[i] = sm; nc[i] = sc2 + lb[path[l] * VD + i];
            }
            for (int i = 0; i < VD; ++i) { Mc[i] = nM[i]; cc[i] = nc[i]; }
        }
    }
    if (t < VD) {
        for (int i = 0; i < VD; ++i) sM[i * VD + t] = Mc[i];
        if (t == 0) for (int i = 0; i < VD; ++i) scb[i] = cc[i];
    }
    __syncthreads();

    // ---------------- epilogue ------------------------------------------
    float2 v[VD];
#pragma unroll
    for (int i = 0; i < VD; ++i) {
        float2 s; s.x = s.y = scb[i];
#pragma unroll
        for (int j = 0; j < VD; ++j) {
            float w = sM[i * VD + j];
            s.x += w * f[j].x; s.y += w * f[j].y;
        }
        v[i] = s;
    }

    float2 n2; n2.x = n2.y = 0.f;
#pragma unroll
    for (int i = 0; i < VD; ++i) { n2.x += v[i].x * v[i].x; n2.y += v[i].y * v[i].y; }
    float2 inv;
    inv.x = 1.f / (sqrtf(n2.x) + 1e-8f);
    inv.y = 1.f / (sqrtf(n2.y) + 1e-8f);
#pragma unroll
    for (int i = 0; i < VD; ++i) { v[i].x *= inv.x; v[i].y *= inv.y; }

    float mb = m2b[0];
    float2 s2; s2.x = s2.y = mb;
#pragma unroll 8
    for (int o = 0; o < 64; ++o) {
        float2 h; h.x = h.y = s1b[o];
#pragma unroll
        for (int i = 0; i < VD; ++i) {
            float w = s1w[o * VD + i];
            h.x += w * v[i].x; h.y += w * v[i].y;
        }
        h.x = fmaxf(h.x, 0.f); h.y = fmaxf(h.y, 0.f);
        float w2 = s2w[o];
        s2.x += w2 * h.x; s2.y += w2 * h.y;
    }
    float psum = s2.x + s2.y;

    const int lane = t & 63, wv = t >> 6;
#pragma unroll
    for (int off = 32; off > 0; off >>= 1) psum += __shfl_down(psum, off);
    if (lane == 0) rs[wv] = psum;
    __syncthreads();

    float* msp = ws + OFF_MSP;
    int* cnt = (int*)(ws + OFF_CNT);
    if (t == 0) {
        ST_AGENT(&msp[b * 8 + bx], rs[0] + rs[1] + rs[2] + rs[3]);   // coherent
        int old = __hip_atomic_fetch_add(cnt, 1, __ATOMIC_ACQ_REL,
                                         __HIP_MEMORY_SCOPE_AGENT);
        lastflag = (old == NB * 8 - 1);
    }
    __syncthreads();

    if (lastflag) {
        if (t < NB) {
            float m = 0.f;
            for (int k = 0; k < 8; ++k)
                m += LD_AGENT(&msp[t * 8 + k]);                      // coherent
            m *= (1.0f / HW);
            out[160 + t] = (1.0f / (1.0f + expf(-m))) * 0.75f + 0.75f;
        }
    }
}

extern "C" void kernel_launch(void* const* d_in, const int* in_sizes, int n_in,
                              void* d_out, int out_size, void* d_ws, size_t ws_size,
                              hipStream_t stream) {
    const float* feat    = (const float*)d_in[0];
    const float* root_w  = (const float*)d_in[1];
    const float* root_b  = (const float*)d_in[2];
    const float* level_w = (const float*)d_in[3];
    const float* level_b = (const float*)d_in[4];
    const float* m1w     = (const float*)d_in[5];
    const float* m1b     = (const float*)d_in[6];
    const float* m2w     = (const float*)d_in[7];
    const float* m2b     = (const float*)d_in[8];
    float* ws  = (float*)d_ws;
    float* out = (float*)d_out;

    k_init<<<32, 256, 0, stream>>>(root_w, ws);
    k_root<<<dim3(16, NB), 256, 0, stream>>>(feat, ws + OFF_WT, root_b,
                                             ws + OFF_P, ws);
    k_final<<<dim3(8, NB), 256, 0, stream>>>(ws + OFF_P, level_w, level_b,
                                             m1w, m1b, m2w, m2b, ws, out);
}